// Round 6
// baseline (294.191 us; speedup 1.0000x reference)
//
#include <hip/hip_runtime.h>
#include <hip/hip_bf16.h>
#include <stdint.h>

// B=2, T=4096, C=512, H=8, D=64. Inputs fp32, output fp32, internals bf16.
// ws (bf16 elems), 32 MiB:
//   Q  [0        .. 4194304)   [B,H,T,D]  (pre-scaled by 0.125*log2e)
//   K  [4194304  .. 8388608)   [B,H,T,D]
//   Vt [8388608  .. 12582912)  [B,H,D,T]
//   Y  [12582912 .. 16777216)  [B,T,C]    (WaT here during QKV; clobbered by attn)
// WpT -> Q region after attn (Q dead). xb (x bf16) in d_out until proj overwrites.
// d_out doubles as attn scratch (xb dead after mm_bt<0>): partial O/rs at [0..8.5MB),
// pair flags at byte offset 12MB (zeroed by prep_a each launch).

typedef __attribute__((ext_vector_type(8))) short short8;
typedef __attribute__((ext_vector_type(4))) float floatx4;
typedef __attribute__((ext_vector_type(16))) float floatx16;
#if __has_builtin(__builtin_amdgcn_permlane32_swap)
typedef __attribute__((ext_vector_type(2))) unsigned int uint2v;
#define HAVE_PLSWAP 1
#else
#define HAVE_PLSWAP 0
#endif

__device__ __forceinline__ unsigned short f2bf(float f) {
    unsigned int x = __float_as_uint(f);
    unsigned int r = x + 0x7fffu + ((x >> 16) & 1u);
    return (unsigned short)(r >> 16);
}

__device__ __forceinline__ unsigned int pk_bf16(float a, float b) {
    __hip_bfloat162 p = __float22bfloat162_rn(make_float2(a, b));  // v_cvt_pk_bf16_f32
    return *reinterpret_cast<unsigned int*>(&p);
}

// ---------------- P0: fused prep: x conv (0..2047) + W_attn^T (2048..2815) + flags ----
__global__ __launch_bounds__(256) void prep_a(
    const float* __restrict__ x, unsigned short* __restrict__ xb,
    const float* __restrict__ Wa, unsigned short* __restrict__ WaT)
{
    const int bid = blockIdx.x;
    const int tid = threadIdx.x;
    if (bid < 2048) {
        size_t i = ((size_t)bid * 256 + tid) * 8;
        float4 a = *reinterpret_cast<const float4*>(x + i);
        float4 b = *reinterpret_cast<const float4*>(x + i + 4);
        unsigned short o[8] = {f2bf(a.x), f2bf(a.y), f2bf(a.z), f2bf(a.w),
                               f2bf(b.x), f2bf(b.y), f2bf(b.z), f2bf(b.w)};
        *reinterpret_cast<uint4*>(xb + i) = *reinterpret_cast<uint4*>(o);
    } else if (bid < 2816) {
        __shared__ unsigned short tile[32][34];
        const int t2 = bid - 2048;           // 48 n-tiles x 16 k-tiles
        const int n0 = (t2 % 48) * 32, k0 = (t2 / 48) * 32;
        const int tx = tid & 31, ty = tid >> 5;
        #pragma unroll
        for (int p = 0; p < 4; ++p)
            tile[tx][ty + p * 8] = f2bf(Wa[(size_t)(k0 + ty + p * 8) * 1536 + n0 + tx]);
        __syncthreads();
        #pragma unroll
        for (int p = 0; p < 4; ++p)
            WaT[(size_t)(n0 + ty + p * 8) * 512 + k0 + tx] = tile[ty + p * 8][tx];
    } else {
        // zero the 512 split-pair flags (d_out byte offset 12 MiB)
        int* fl = reinterpret_cast<int*>(xb) + 3145728;
        fl[tid] = 0;
        fl[tid + 256] = 0;
    }
}

// ---------------- P1: W_proj [512][512] fp32 -> WpT [512][512] bf16 -------------------
__global__ __launch_bounds__(256) void transpose_wp(
    const float* __restrict__ W, unsigned short* __restrict__ Wt)
{
    __shared__ unsigned short tile[32][34];
    const int tid = threadIdx.x;
    const int tx = tid & 31, ty = tid >> 5;
    const int n0 = blockIdx.x * 32, k0 = blockIdx.y * 32;
    #pragma unroll
    for (int p = 0; p < 4; ++p)
        tile[tx][ty + p * 8] = f2bf(W[(size_t)(k0 + ty + p * 8) * 512 + n0 + tx]);
    __syncthreads();
    #pragma unroll
    for (int p = 0; p < 4; ++p)
        Wt[(size_t)(n0 + ty + p * 8) * 512 + k0 + tx] = tile[ty + p * 8][tx];
}

// ---------------- MFMA GEMM (r16-proven): 128x128, BK=32, LDS dbuf, 1 barrier/iter ----
template<int EPI>
__global__ __launch_bounds__(256) void mm_bt(
    const unsigned short* __restrict__ A,
    const unsigned short* __restrict__ Bt,
    void* __restrict__ outp)
{
    __shared__ __align__(16) unsigned char smem[40960];

    const int tid  = threadIdx.x;
    const int wave = tid >> 6;
    const int lane = tid & 63;
    const int quad = lane >> 4;
    const int l16  = lane & 15;
    const int wr   = wave >> 1;
    const int wc   = wave & 1;
    const int m0 = blockIdx.x * 128;
    const int n0 = blockIdx.y * 128;

    floatx4 acc[4][4];
    #pragma unroll
    for (int i = 0; i < 4; ++i)
        #pragma unroll
        for (int j = 0; j < 4; ++j) acc[i][j] = (floatx4){0.f, 0.f, 0.f, 0.f};

    const int row = tid >> 1;
    const int cb  = (tid & 1) * 16;

    const unsigned short* ap = &A[(size_t)(m0 + row) * 512 + cb];
    const unsigned short* bp = &Bt[(size_t)(n0 + row) * 512 + cb];

    uint4 ra0 = *reinterpret_cast<const uint4*>(ap);
    uint4 ra1 = *reinterpret_cast<const uint4*>(ap + 8);
    uint4 rb0 = *reinterpret_cast<const uint4*>(bp);
    uint4 rb1 = *reinterpret_cast<const uint4*>(bp + 8);
    {
        auto Al = reinterpret_cast<unsigned short(*)[40]>(smem);
        auto Bl = reinterpret_cast<unsigned short(*)[40]>(smem + 10240);
        *reinterpret_cast<uint4*>(&Al[row][cb])     = ra0;
        *reinterpret_cast<uint4*>(&Al[row][cb + 8]) = ra1;
        *reinterpret_cast<uint4*>(&Bl[row][cb])     = rb0;
        *reinterpret_cast<uint4*>(&Bl[row][cb + 8]) = rb1;
    }

    for (int it = 0; it < 16; ++it) {
        __syncthreads();
        const int k0 = it * 32;
        if (it < 15) {
            ra0 = *reinterpret_cast<const uint4*>(ap + k0 + 32);
            ra1 = *reinterpret_cast<const uint4*>(ap + k0 + 40);
            rb0 = *reinterpret_cast<const uint4*>(bp + k0 + 32);
            rb1 = *reinterpret_cast<const uint4*>(bp + k0 + 40);
        }

        auto Al = reinterpret_cast<unsigned short(*)[40]>(smem + (it & 1) * 20480);
        auto Bl = reinterpret_cast<unsigned short(*)[40]>(smem + (it & 1) * 20480 + 10240);

        short8 af[4], bf[4];
        #pragma unroll
        for (int ti = 0; ti < 4; ++ti)
            af[ti] = *reinterpret_cast<const short8*>(&Al[wr * 64 + ti * 16 + l16][quad * 8]);
        #pragma unroll
        for (int tj = 0; tj < 4; ++tj)
            bf[tj] = *reinterpret_cast<const short8*>(&Bl[wc * 64 + tj * 16 + l16][quad * 8]);
        #pragma unroll
        for (int ti = 0; ti < 4; ++ti)
            #pragma unroll
            for (int tj = 0; tj < 4; ++tj)
                acc[ti][tj] = __builtin_amdgcn_mfma_f32_16x16x32_bf16(af[ti], bf[tj], acc[ti][tj], 0, 0, 0);

        if (it < 15) {
            auto An = reinterpret_cast<unsigned short(*)[40]>(smem + ((it + 1) & 1) * 20480);
            auto Bn = reinterpret_cast<unsigned short(*)[40]>(smem + ((it + 1) & 1) * 20480 + 10240);
            *reinterpret_cast<uint4*>(&An[row][cb])     = ra0;
            *reinterpret_cast<uint4*>(&An[row][cb + 8]) = ra1;
            *reinterpret_cast<uint4*>(&Bn[row][cb])     = rb0;
            *reinterpret_cast<uint4*>(&Bn[row][cb + 8]) = rb1;
        }
    }

    if (EPI == 0) {
        unsigned short* WS = (unsigned short*)outp;
        unsigned short* Qb  = WS;
        unsigned short* Kb  = WS + 4194304;
        unsigned short* Vtb = WS + 8388608;
        const int which = n0 >> 9;
        const int h = ((n0 + wc * 64) >> 6) & 7;

        if (which == 2) {
            auto Tr = reinterpret_cast<unsigned short(*)[80]>(smem);   // [256][80]
            __syncthreads();
            #pragma unroll
            for (int ti = 0; ti < 4; ++ti)
                #pragma unroll
                for (int tj = 0; tj < 4; ++tj) {
                    unsigned int lo = pk_bf16(acc[ti][tj][0], acc[ti][tj][1]);
                    unsigned int hi = pk_bf16(acc[ti][tj][2], acc[ti][tj][3]);
                    *reinterpret_cast<uint2*>(&Tr[(wave << 6) + tj * 16 + l16][ti * 16 + quad * 4])
                        = make_uint2(lo, hi);
                }
            const int b = m0 >> 12;
            const int bh = b * 8 + h;
            const int t0g = (m0 & 4095) + wr * 64;
            const int tseg = (lane & 7) * 8;
            #pragma unroll
            for (int p = 0; p < 8; ++p) {
                int dl = p * 8 + (lane >> 3);
                uint4 v = *reinterpret_cast<const uint4*>(&Tr[(wave << 6) + dl][tseg]);
                *reinterpret_cast<uint4*>(&Vtb[((size_t)(bh * 64 + dl)) * 4096 + t0g + tseg]) = v;
            }
        } else {
            const float sc = (which == 0) ? 0.18033688f : 1.0f;  // 0.125*log2(e)
            #pragma unroll
            for (int ti = 0; ti < 4; ++ti) {
                #pragma unroll
                for (int r = 0; r < 4; ++r) {
                    int m = m0 + wr * 64 + ti * 16 + quad * 4 + r;
                    int b = m >> 12, t = m & 4095;
                    int bh = b * 8 + h;
                    #pragma unroll
                    for (int tj = 0; tj < 4; ++tj) {
                        int d = tj * 16 + l16;
                        unsigned short val = f2bf(acc[ti][tj][r] * sc);
                        if (which == 0) Qb[((size_t)bh * 4096 + t) * 64 + d] = val;
                        else            Kb[((size_t)bh * 4096 + t) * 64 + d] = val;
                    }
                }
            }
        }
    } else {
        float* Out = (float*)outp;
        #pragma unroll
        for (int ti = 0; ti < 4; ++ti) {
            #pragma unroll
            for (int r = 0; r < 4; ++r) {
                int m = m0 + wr * 64 + ti * 16 + quad * 4 + r;
                #pragma unroll
                for (int tj = 0; tj < 4; ++tj) {
                    int n = n0 + wc * 64 + tj * 16 + l16;
                    Out[(size_t)m * 512 + n] = acc[ti][tj][r];
                }
            }
        }
    }
}

// ---------------- MFMA flash attention: r5 core + uniform-short blocks (key-split) ----
// Block = 64 q-rows, 4 waves split-K (p=wave>>1 q-half, w=wave&1 key-half), LDS 32 KB.
// Long causal rows split: qb 32..63 -> two blocks over key-ranges [0,T/2), [T/2,T).
// Grid 1536 = 6 layers x 256 CUs; per-CU lifetimes all <=32 tiles, sum 130 ->
// sustained ~4 blocks/CU (16 waves) vs r5's decaying 2.3 (23% occ, latency-bound).
// Split pairs combine via ticket atomic: first finisher writes partial O(f32)+rs to
// d_out scratch, fences, releases; second combines + writes Y. Ticket-0 never waits
// -> deadlock-free under any residency. Rowsum via ones-MFMA into o4 (VALU -> MFMA).
__global__ __launch_bounds__(256) void attn_mfma(
    const unsigned short* __restrict__ Q,
    const unsigned short* __restrict__ K,
    const unsigned short* __restrict__ Vt,
    unsigned short* __restrict__ Y,
    float* __restrict__ scratch, int* __restrict__ flags)
{
    __shared__ __align__(16) unsigned short Kc[2][64][64];
    __shared__ __align__(16) unsigned short Vc[2][64][64];

    const int tid  = threadIdx.x;
    const int wave = tid >> 6;
    const int lane = tid & 63;
    const int l32  = lane & 31;
    const int hh   = lane >> 5;
    const int swz  = l32 & 7;
    const int p    = wave >> 1;      // q-half of block (rows m0+32p .. +31)
    const int w    = wave & 1;       // key-half of tile (keys 32w .. 32w+31)

    // layered block decode: CU c = bid&255 hosts j=c>>4, bh=c&15; layer g = bid>>8.
    // g0/g1: split(63-j) H/L; g2: qb=31-j; g3/g4: split(32+j) H/L; g5: qb=j.
    const int bid = blockIdx.x;
    const int cu  = bid & 255;
    const int bh  = cu & 15;
    const int j   = cu >> 4;
    const int g   = bid >> 8;
    int qb, t0, t1;
    if      (g == 0) { qb = 63 - j; t0 = (64 - j) >> 1; t1 = 64 - j; }
    else if (g == 1) { qb = 63 - j; t0 = 0;             t1 = (64 - j) >> 1; }
    else if (g == 2) { qb = 31 - j; t0 = 0;             t1 = 32 - j; }
    else if (g == 3) { qb = 32 + j; t0 = (33 + j) >> 1; t1 = 33 + j; }
    else if (g == 4) { qb = 32 + j; t0 = 0;             t1 = (33 + j) >> 1; }
    else             { qb = j;      t0 = 0;             t1 = j + 1; }
    const bool split = (g != 2) && (g != 5);
    const int m0 = qb * 64;

    const unsigned short* Qp = Q  + (size_t)bh * (4096 * 64);
    const unsigned short* Kp = K  + (size_t)bh * (4096 * 64);
    const unsigned short* Vp = Vt + (size_t)bh * (64 * 4096);

    // Q B-frags (pre-scaled upstream): col q = m0+32p+l32, k(d) = k16*16 + hh*8 + jj
    short8 qf[4];
    #pragma unroll
    for (int k16 = 0; k16 < 4; ++k16)
        qf[k16] = *reinterpret_cast<const short8*>(
            &Qp[(size_t)(m0 + 32 * p + l32) * 64 + k16 * 16 + hh * 8]);

    short8 ones;
    #pragma unroll
    for (int i = 0; i < 8; ++i) ones[i] = (short)0x3F80;

    floatx16 o0 = {0,0,0,0,0,0,0,0,0,0,0,0,0,0,0,0};   // O[q][d=l32]
    floatx16 o1 = {0,0,0,0,0,0,0,0,0,0,0,0,0,0,0,0};   // O[q][d=32+l32]
    floatx16 o4 = {0,0,0,0,0,0,0,0,0,0,0,0,0,0,0,0};   // rowsum (ones-MFMA)

    // staging: thread covers rows rr, rr+32 at 16B chunk cc; XOR-swizzled (r1-proven)
    const int rr  = tid >> 3;
    const int cc  = tid & 7;
    const int c0  = cc * 8;
    const int scs = ((cc ^ (rr & 7)) << 3);
    const int kb0 = t0 * 64;

    uint4 rk0 = *reinterpret_cast<const uint4*>(&Kp[(size_t)(kb0 + rr) * 64 + c0]);
    uint4 rk1 = *reinterpret_cast<const uint4*>(&Kp[(size_t)(kb0 + rr + 32) * 64 + c0]);
    uint4 rv0 = *reinterpret_cast<const uint4*>(&Vp[(size_t)rr * 4096 + kb0 + c0]);
    uint4 rv1 = *reinterpret_cast<const uint4*>(&Vp[(size_t)(rr + 32) * 4096 + kb0 + c0]);
    *reinterpret_cast<uint4*>(&Kc[0][rr][scs])      = rk0;
    *reinterpret_cast<uint4*>(&Kc[0][rr + 32][scs]) = rk1;
    *reinterpret_cast<uint4*>(&Vc[0][rr][scs])      = rv0;
    *reinterpret_cast<uint4*>(&Vc[0][rr + 32][scs]) = rv1;

    for (int kt = t0; kt < t1; ++kt) {
        __syncthreads();
        const int lt  = kt - t0;
        const int cur = lt & 1;
        const int nxt = cur ^ 1;

        if (kt + 1 < t1) {   // prefetch next tile into registers
            const int jn = (kt + 1) * 64;
            rk0 = *reinterpret_cast<const uint4*>(&Kp[(size_t)(jn + rr) * 64 + c0]);
            rk1 = *reinterpret_cast<const uint4*>(&Kp[(size_t)(jn + rr + 32) * 64 + c0]);
            rv0 = *reinterpret_cast<const uint4*>(&Vp[(size_t)rr * 4096 + jn + c0]);
            rv1 = *reinterpret_cast<const uint4*>(&Vp[(size_t)(rr + 32) * 4096 + jn + c0]);
        }

        // only fully-masked case: q-half 0's key-half 1 on the diagonal tile
        const bool active = (kt < qb) || (w == 0) || (p == 1);
        if (active) {
            // ---- QK^T: S[key][q], A = K rows 32w+l32, B = Q ----
            floatx16 s = {0,0,0,0,0,0,0,0,0,0,0,0,0,0,0,0};
            #pragma unroll
            for (int k16 = 0; k16 < 4; ++k16) {
                const int chs = ((2 * k16 + hh) ^ swz) << 3;
                short8 a = *reinterpret_cast<const short8*>(&Kc[cur][32 * w + l32][chs]);
                s = __builtin_amdgcn_mfma_f32_32x32x16_bf16(a, qf[k16], s, 0, 0, 0);
            }
            if (kt == qb) {   // diagonal: key_local = 32w + (r&3)+8*(r>>2)+4*hh
                const int ql = 32 * p + l32;
                #pragma unroll
                for (int r = 0; r < 16; ++r) {
                    const int kl = 32 * w + (r & 3) + 8 * (r >> 2) + 4 * hh;
                    s[r] = (kl <= ql) ? s[r] : -1e30f;
                }
            }
            #pragma unroll
            for (int r = 0; r < 16; ++r) s[r] = __builtin_amdgcn_exp2f(s[r]);

            // ---- P -> PV A-frags in registers (r4/r5-verified construction) ----
            unsigned int A0 = pk_bf16(s[0],  s[1]),  B0 = pk_bf16(s[2],  s[3]);
            unsigned int A1 = pk_bf16(s[4],  s[5]),  B1 = pk_bf16(s[6],  s[7]);
            unsigned int A2 = pk_bf16(s[8],  s[9]),  B2 = pk_bf16(s[10], s[11]);
            unsigned int A3 = pk_bf16(s[12], s[13]), B3 = pk_bf16(s[14], s[15]);
            short8 pa[2];
#if HAVE_PLSWAP
            {
                uint2v rA = __builtin_amdgcn_permlane32_swap(A0, A1, false, false);
                uint2v rB = __builtin_amdgcn_permlane32_swap(B0, B1, false, false);
                uint4 u0 = make_uint4(rA[0], rB[0], rA[1], rB[1]);
                pa[0] = *reinterpret_cast<short8*>(&u0);
                rA = __builtin_amdgcn_permlane32_swap(A2, A3, false, false);
                rB = __builtin_amdgcn_permlane32_swap(B2, B3, false, false);
                uint4 u1 = make_uint4(rA[0], rB[0], rA[1], rB[1]);
                pa[1] = *reinterpret_cast<short8*>(&u1);
            }
#else
            {
                unsigned int pA0 = __shfl_xor((int)A0, 32), pA1 = __shfl_xor((int)A1, 32);
                unsigned int pB0 = __shfl_xor((int)B0, 32), pB1 = __shfl_xor((int)B1, 32);
                unsigned int pA2 = __shfl_xor((int)A2, 32), pA3 = __shfl_xor((int)A3, 32);
                unsigned int pB2 = __shfl_xor((int)B2, 32), pB3 = __shfl_xor((int)B3, 32);
                uint4 u0 = make_uint4(hh ? pA1 : A0, hh ? pB1 : B0,
                                      hh ? A1 : pA0, hh ? B1 : pB0);
                pa[0] = *reinterpret_cast<short8*>(&u0);
                uint4 u1 = make_uint4(hh ? pA3 : A2, hh ? pB3 : B2,
                                      hh ? A3 : pA2, hh ? B3 : pB2);
                pa[1] = *reinterpret_cast<short8*>(&u1);
            }
#endif
            // rowsum on the MFMA pipe (same bf16 P values as PV consumes)
            o4 = __builtin_amdgcn_mfma_f32_32x32x16_bf16(pa[0], ones, o4, 0, 0, 0);
            o4 = __builtin_amdgcn_mfma_f32_32x32x16_bf16(pa[1], ones, o4, 0, 0, 0);

            // ---- PV: O[q][d] over key window 32w..32w+31; B = V[key][d] ----
            #pragma unroll
            for (int f = 0; f < 2; ++f) {
                const int chs = ((4 * w + 2 * f + hh) ^ swz) << 3;
                short8 b0 = *reinterpret_cast<const short8*>(&Vc[cur][l32][chs]);
                short8 b1 = *reinterpret_cast<const short8*>(&Vc[cur][32 + l32][chs]);
                o0 = __builtin_amdgcn_mfma_f32_32x32x16_bf16(pa[f], b0, o0, 0, 0, 0);
                o1 = __builtin_amdgcn_mfma_f32_32x32x16_bf16(pa[f], b1, o1, 0, 0, 0);
            }
        }

        if (kt + 1 < t1) {   // stage prefetched tile into the idle buffer
            *reinterpret_cast<uint4*>(&Kc[nxt][rr][scs])      = rk0;
            *reinterpret_cast<uint4*>(&Kc[nxt][rr + 32][scs]) = rk1;
            *reinterpret_cast<uint4*>(&Vc[nxt][rr][scs])      = rv0;
            *reinterpret_cast<uint4*>(&Vc[nxt][rr + 32][scs]) = rv1;
        }
    }

    // ---- epilogue: combine partial O + rowsum across the wave pair via LDS ----
    __syncthreads();                                       // all tile reads done
    float* Ob  = reinterpret_cast<float*>(&Kc[0][0][0]);   // [4][32][32] f32 = 16 KB
    float* Wsf = reinterpret_cast<float*>(&Vc[0][0][0]);   // [4][32] rowsums by q
    if (l32 == 0) {
        #pragma unroll
        for (int r = 0; r < 16; ++r) {
            const int qloc = (r & 3) + 8 * (r >> 2) + 4 * hh;
            Wsf[(p * 2 + w) * 32 + qloc] = o4[r];          // o4 duplicated across cols
        }
    }
    #pragma unroll
    for (int r = 0; r < 16; ++r) {                         // give away the partner half
        const int qloc = (r & 3) + 8 * (r >> 2) + 4 * hh;
        Ob[((p * 2 + w) * 32 + qloc) * 32 + l32] = w ? o0[r] : o1[r];
    }
    __syncthreads();

    float cmb[16], rt[16];
    #pragma unroll
    for (int gg = 0; gg < 4; ++gg) {
        float4 a4 = *reinterpret_cast<const float4*>(&Wsf[(p * 2 + 0) * 32 + 8 * gg + 4 * hh]);
        float4 b4 = *reinterpret_cast<const float4*>(&Wsf[(p * 2 + 1) * 32 + 8 * gg + 4 * hh]);
        const float ra[4] = {a4.x + b4.x, a4.y + b4.y, a4.z + b4.z, a4.w + b4.w};
        #pragma unroll
        for (int rsub = 0; rsub < 4; ++rsub) {
            const int r = gg * 4 + rsub;
            const int qloc = 8 * gg + 4 * hh + rsub;
            cmb[r] = (w ? o1[r] : o0[r]) + Ob[((p * 2 + (1 - w)) * 32 + qloc) * 32 + l32];
            rt[r]  = ra[rsub];
        }
    }

    const int b = bh >> 3, h = bh & 7;
    if (!split) {
        #pragma unroll
        for (int r = 0; r < 16; ++r) {
            const int qloc = (r & 3) + 8 * (r >> 2) + 4 * hh;
            const int t = m0 + 32 * p + qloc;
            Y[((size_t)(b * 4096 + t)) * 512 + h * 64 + 32 * w + l32] = f2bf(cmb[r] / rt[r]);
        }
        return;
    }

    // ---- split pair: ticket protocol (first writes partial, second combines) ----
    const int pid = bh * 32 + (qb - 32);
    float* slotO  = scratch + (size_t)pid * 4160;          // 64x64 O + 64 rs
    float* slotRs = slotO + 4096;
    int* flagp = flags + pid;
    volatile int* shv = reinterpret_cast<volatile int*>(Wsf) + 200;  // spare LDS int
    __syncthreads();                                       // Wsf reads above done
    if (tid == 0) *shv = atomicAdd(flagp, 1);
    __syncthreads();
    const int ticket = *shv;

    if (ticket == 0) {                                     // first: publish partial
        #pragma unroll
        for (int r = 0; r < 16; ++r) {
            const int qloc = (r & 3) + 8 * (r >> 2) + 4 * hh;
            slotO[(32 * p + qloc) * 64 + 32 * w + l32] = cmb[r];
        }
        if (tid < 64) slotRs[tid] = Wsf[(tid >> 5) * 64 + (tid & 31)]
                                  + Wsf[(tid >> 5) * 64 + 32 + (tid & 31)];
        __threadfence();                                   // release
        __syncthreads();
        if (tid == 0) atomicAdd(flagp, 1);
        return;
    }
    // second: wait for release (ticket-0 block is already executing -> bounded)
    if (tid == 0) { while (atomicAdd(flagp, 0) < 2) __builtin_amdgcn_s_sleep(4); }
    __syncthreads();
    __threadfence();                                       // acquire
    #pragma unroll
    for (int gg = 0; gg < 4; ++gg) {
        float4 pr = *reinterpret_cast<const float4*>(&slotRs[32 * p + 8 * gg + 4 * hh]);
        const float prr[4] = {pr.x, pr.y, pr.z, pr.w};
        #pragma unroll
        for (int rsub = 0; rsub < 4; ++rsub) {
            const int r = gg * 4 + rsub;
            const int qloc = 8 * gg + 4 * hh + rsub;
            const float po = slotO[(32 * p + qloc) * 64 + 32 * w + l32];
            const int t = m0 + 32 * p + qloc;
            Y[((size_t)(b * 4096 + t)) * 512 + h * 64 + 32 * w + l32]
                = f2bf((cmb[r] + po) / (rt[r] + prr[rsub]));
        }
    }
}

extern "C" void kernel_launch(void* const* d_in, const int* in_sizes, int n_in,
                              void* d_out, int out_size, void* d_ws, size_t ws_size,
                              hipStream_t stream) {
    const float* x  = (const float*)d_in[0];
    const float* Wa = (const float*)d_in[1];
    const float* Wp = (const float*)d_in[2];
    float* out = (float*)d_out;
    unsigned short* ws = (unsigned short*)d_ws;

    unsigned short* Qb  = ws;
    unsigned short* Kb  = ws + 4194304;
    unsigned short* Vtb = ws + 8388608;
    unsigned short* Yb  = ws + 12582912;
    unsigned short* WaT = Yb;                      // W_attn^T during QKV only
    unsigned short* WpT = Qb;                      // W_proj^T after attn (Q dead)
    unsigned short* xb  = (unsigned short*)d_out;  // x bf16; overwritten by proj
    float* scratch = (float*)d_out;                // partial O/rs during attn (xb dead)
    int*   flags   = (int*)d_out + 3145728;        // 512 pair flags @ 12 MiB

    prep_a<<<dim3(2817), dim3(256), 0, stream>>>(x, xb, Wa, WaT);
    mm_bt<0><<<dim3(64, 12), dim3(256), 0, stream>>>(xb, WaT, (void*)ws);
    attn_mfma<<<dim3(1536), dim3(256), 0, stream>>>(Qb, Kb, Vtb, Yb, scratch, flags);
    transpose_wp<<<dim3(16, 16), dim3(256), 0, stream>>>(Wp, WpT);
    mm_bt<1><<<dim3(64, 4), dim3(256), 0, stream>>>(Yb, WpT, (void*)out);
}

// Round 7
// 199.699 us; speedup vs baseline: 1.4732x; 1.4732x over previous
//
#include <hip/hip_runtime.h>
#include <hip/hip_bf16.h>
#include <stdint.h>

// B=2, T=4096, C=512, H=8, D=64. Inputs fp32, output fp32, internals bf16.
// ws (bf16 elems), 32 MiB:
//   Q  [0        .. 4194304)   [B,H,T,D]  (pre-scaled by 0.125*log2e)
//   K  [4194304  .. 8388608)   [B,H,T,D]
//   Vt [8388608  .. 12582912)  [B,H,D,T]
//   Y  [12582912 .. 16777216)  [B,T,C]    (WaT here during QKV; clobbered by attn)
// WpT -> Q region after attn (Q dead). xb (x bf16) in d_out until proj overwrites.
// During attn, d_out (xb dead) holds split-row partial O: A-slots f32 [0..8.39MB),
// B-slots [8.39..16.78MB). Partial rowsums live as f32 inside the (unwritten) Y rows
// that attn_fin itself overwrites after reading. No atomics, no flags, no spin.

typedef __attribute__((ext_vector_type(8))) short short8;
typedef __attribute__((ext_vector_type(4))) float floatx4;
typedef __attribute__((ext_vector_type(16))) float floatx16;
#if __has_builtin(__builtin_amdgcn_permlane32_swap)
typedef __attribute__((ext_vector_type(2))) unsigned int uint2v;
#define HAVE_PLSWAP 1
#else
#define HAVE_PLSWAP 0
#endif

__device__ __forceinline__ unsigned short f2bf(float f) {
    unsigned int x = __float_as_uint(f);
    unsigned int r = x + 0x7fffu + ((x >> 16) & 1u);
    return (unsigned short)(r >> 16);
}

__device__ __forceinline__ unsigned int pk_bf16(float a, float b) {
    __hip_bfloat162 p = __float22bfloat162_rn(make_float2(a, b));  // v_cvt_pk_bf16_f32
    return *reinterpret_cast<unsigned int*>(&p);
}

// ---------------- P0: fused prep: convert x (blocks 0..2047) + W_attn^T (2048..2815) --
__global__ __launch_bounds__(256) void prep_a(
    const float* __restrict__ x, unsigned short* __restrict__ xb,
    const float* __restrict__ Wa, unsigned short* __restrict__ WaT)
{
    const int bid = blockIdx.x;
    const int tid = threadIdx.x;
    if (bid < 2048) {
        size_t i = ((size_t)bid * 256 + tid) * 8;
        float4 a = *reinterpret_cast<const float4*>(x + i);
        float4 b = *reinterpret_cast<const float4*>(x + i + 4);
        unsigned short o[8] = {f2bf(a.x), f2bf(a.y), f2bf(a.z), f2bf(a.w),
                               f2bf(b.x), f2bf(b.y), f2bf(b.z), f2bf(b.w)};
        *reinterpret_cast<uint4*>(xb + i) = *reinterpret_cast<uint4*>(o);
    } else {
        __shared__ unsigned short tile[32][34];
        const int t2 = bid - 2048;           // 48 n-tiles x 16 k-tiles
        const int n0 = (t2 % 48) * 32, k0 = (t2 / 48) * 32;
        const int tx = tid & 31, ty = tid >> 5;
        #pragma unroll
        for (int p = 0; p < 4; ++p)
            tile[tx][ty + p * 8] = f2bf(Wa[(size_t)(k0 + ty + p * 8) * 1536 + n0 + tx]);
        __syncthreads();
        #pragma unroll
        for (int p = 0; p < 4; ++p)
            WaT[(size_t)(n0 + ty + p * 8) * 512 + k0 + tx] = tile[ty + p * 8][tx];
    }
}

// ---------------- P1: W_proj [512][512] fp32 -> WpT [512][512] bf16 -------------------
__global__ __launch_bounds__(256) void transpose_wp(
    const float* __restrict__ W, unsigned short* __restrict__ Wt)
{
    __shared__ unsigned short tile[32][34];
    const int tid = threadIdx.x;
    const int tx = tid & 31, ty = tid >> 5;
    const int n0 = blockIdx.x * 32, k0 = blockIdx.y * 32;
    #pragma unroll
    for (int p = 0; p < 4; ++p)
        tile[tx][ty + p * 8] = f2bf(W[(size_t)(k0 + ty + p * 8) * 512 + n0 + tx]);
    __syncthreads();
    #pragma unroll
    for (int p = 0; p < 4; ++p)
        Wt[(size_t)(n0 + ty + p * 8) * 512 + k0 + tx] = tile[ty + p * 8][tx];
}

// ---------------- MFMA GEMM (r16-proven): 128x128, BK=32, LDS dbuf, 1 barrier/iter ----
template<int EPI>
__global__ __launch_bounds__(256) void mm_bt(
    const unsigned short* __restrict__ A,
    const unsigned short* __restrict__ Bt,
    void* __restrict__ outp)
{
    __shared__ __align__(16) unsigned char smem[40960];

    const int tid  = threadIdx.x;
    const int wave = tid >> 6;
    const int lane = tid & 63;
    const int quad = lane >> 4;
    const int l16  = lane & 15;
    const int wr   = wave >> 1;
    const int wc   = wave & 1;
    const int m0 = blockIdx.x * 128;
    const int n0 = blockIdx.y * 128;

    floatx4 acc[4][4];
    #pragma unroll
    for (int i = 0; i < 4; ++i)
        #pragma unroll
        for (int j = 0; j < 4; ++j) acc[i][j] = (floatx4){0.f, 0.f, 0.f, 0.f};

    const int row = tid >> 1;
    const int cb  = (tid & 1) * 16;

    const unsigned short* ap = &A[(size_t)(m0 + row) * 512 + cb];
    const unsigned short* bp = &Bt[(size_t)(n0 + row) * 512 + cb];

    uint4 ra0 = *reinterpret_cast<const uint4*>(ap);
    uint4 ra1 = *reinterpret_cast<const uint4*>(ap + 8);
    uint4 rb0 = *reinterpret_cast<const uint4*>(bp);
    uint4 rb1 = *reinterpret_cast<const uint4*>(bp + 8);
    {
        auto Al = reinterpret_cast<unsigned short(*)[40]>(smem);
        auto Bl = reinterpret_cast<unsigned short(*)[40]>(smem + 10240);
        *reinterpret_cast<uint4*>(&Al[row][cb])     = ra0;
        *reinterpret_cast<uint4*>(&Al[row][cb + 8]) = ra1;
        *reinterpret_cast<uint4*>(&Bl[row][cb])     = rb0;
        *reinterpret_cast<uint4*>(&Bl[row][cb + 8]) = rb1;
    }

    for (int it = 0; it < 16; ++it) {
        __syncthreads();
        const int k0 = it * 32;
        if (it < 15) {
            ra0 = *reinterpret_cast<const uint4*>(ap + k0 + 32);
            ra1 = *reinterpret_cast<const uint4*>(ap + k0 + 40);
            rb0 = *reinterpret_cast<const uint4*>(bp + k0 + 32);
            rb1 = *reinterpret_cast<const uint4*>(bp + k0 + 40);
        }

        auto Al = reinterpret_cast<unsigned short(*)[40]>(smem + (it & 1) * 20480);
        auto Bl = reinterpret_cast<unsigned short(*)[40]>(smem + (it & 1) * 20480 + 10240);

        short8 af[4], bf[4];
        #pragma unroll
        for (int ti = 0; ti < 4; ++ti)
            af[ti] = *reinterpret_cast<const short8*>(&Al[wr * 64 + ti * 16 + l16][quad * 8]);
        #pragma unroll
        for (int tj = 0; tj < 4; ++tj)
            bf[tj] = *reinterpret_cast<const short8*>(&Bl[wc * 64 + tj * 16 + l16][quad * 8]);
        #pragma unroll
        for (int ti = 0; ti < 4; ++ti)
            #pragma unroll
            for (int tj = 0; tj < 4; ++tj)
                acc[ti][tj] = __builtin_amdgcn_mfma_f32_16x16x32_bf16(af[ti], bf[tj], acc[ti][tj], 0, 0, 0);

        if (it < 15) {
            auto An = reinterpret_cast<unsigned short(*)[40]>(smem + ((it + 1) & 1) * 20480);
            auto Bn = reinterpret_cast<unsigned short(*)[40]>(smem + ((it + 1) & 1) * 20480 + 10240);
            *reinterpret_cast<uint4*>(&An[row][cb])     = ra0;
            *reinterpret_cast<uint4*>(&An[row][cb + 8]) = ra1;
            *reinterpret_cast<uint4*>(&Bn[row][cb])     = rb0;
            *reinterpret_cast<uint4*>(&Bn[row][cb + 8]) = rb1;
        }
    }

    if (EPI == 0) {
        unsigned short* WS = (unsigned short*)outp;
        unsigned short* Qb  = WS;
        unsigned short* Kb  = WS + 4194304;
        unsigned short* Vtb = WS + 8388608;
        const int which = n0 >> 9;
        const int h = ((n0 + wc * 64) >> 6) & 7;

        if (which == 2) {
            auto Tr = reinterpret_cast<unsigned short(*)[80]>(smem);   // [256][80]
            __syncthreads();
            #pragma unroll
            for (int ti = 0; ti < 4; ++ti)
                #pragma unroll
                for (int tj = 0; tj < 4; ++tj) {
                    unsigned int lo = pk_bf16(acc[ti][tj][0], acc[ti][tj][1]);
                    unsigned int hi = pk_bf16(acc[ti][tj][2], acc[ti][tj][3]);
                    *reinterpret_cast<uint2*>(&Tr[(wave << 6) + tj * 16 + l16][ti * 16 + quad * 4])
                        = make_uint2(lo, hi);
                }
            const int b = m0 >> 12;
            const int bh = b * 8 + h;
            const int t0g = (m0 & 4095) + wr * 64;
            const int tseg = (lane & 7) * 8;
            #pragma unroll
            for (int p = 0; p < 8; ++p) {
                int dl = p * 8 + (lane >> 3);
                uint4 v = *reinterpret_cast<const uint4*>(&Tr[(wave << 6) + dl][tseg]);
                *reinterpret_cast<uint4*>(&Vtb[((size_t)(bh * 64 + dl)) * 4096 + t0g + tseg]) = v;
            }
        } else {
            const float sc = (which == 0) ? 0.18033688f : 1.0f;  // 0.125*log2(e)
            #pragma unroll
            for (int ti = 0; ti < 4; ++ti) {
                #pragma unroll
                for (int r = 0; r < 4; ++r) {
                    int m = m0 + wr * 64 + ti * 16 + quad * 4 + r;
                    int b = m >> 12, t = m & 4095;
                    int bh = b * 8 + h;
                    #pragma unroll
                    for (int tj = 0; tj < 4; ++tj) {
                        int d = tj * 16 + l16;
                        unsigned short val = f2bf(acc[ti][tj][r] * sc);
                        if (which == 0) Qb[((size_t)bh * 4096 + t) * 64 + d] = val;
                        else            Kb[((size_t)bh * 4096 + t) * 64 + d] = val;
                    }
                }
            }
        }
    } else {
        float* Out = (float*)outp;
        #pragma unroll
        for (int ti = 0; ti < 4; ++ti) {
            #pragma unroll
            for (int r = 0; r < 4; ++r) {
                int m = m0 + wr * 64 + ti * 16 + quad * 4 + r;
                #pragma unroll
                for (int tj = 0; tj < 4; ++tj) {
                    int n = n0 + wc * 64 + tj * 16 + l16;
                    Out[(size_t)m * 512 + n] = acc[ti][tj][r];
                }
            }
        }
    }
}

// ---------------- MFMA flash attention: r5 core + uniform-lifetime chains -------------
// 1024 blocks, each a chain of 1-2 items totaling 32-33 tiles (UNIFORM lifetime):
//   c<32 : B-item {qb=32+c, tiles c+1..c+32+diag} (32 tiles, partial -> slotB)
//   c<48 : A-pair {qb=32+s, tiles 0..s} + {qb=63-s, tiles 0..31-s} (33, partial->slotA)
//   else : whole-pair {qb=u} + {qb=31-u} (33 tiles, direct Y writes)
// 4 blocks/CU, all resident t=0, all finish together -> sustained 16 waves/CU (r5's
// 23%-decaying occupancy was the binder). No atomics/flags/spin (r6 lesson). Split
// combine is ordering-free: disjoint f32 slots in d_out; attn_fin (next kernel =
// global barrier) adds + normalizes. Rowsum via ones-MFMA (off the VALU pipe).
__global__ __launch_bounds__(256) void attn_mfma(
    const unsigned short* __restrict__ Q,
    const unsigned short* __restrict__ K,
    const unsigned short* __restrict__ Vt,
    unsigned short* __restrict__ Y,
    float* __restrict__ scratch)
{
    __shared__ __align__(16) unsigned short Kc[2][64][64];
    __shared__ __align__(16) unsigned short Vc[2][64][64];

    const int tid  = threadIdx.x;
    const int wave = tid >> 6;
    const int lane = tid & 63;
    const int l32  = lane & 31;
    const int hh   = lane >> 5;
    const int swz  = l32 & 7;
    const int p    = wave >> 1;      // q-half of block (rows m0+32p .. +31)
    const int w    = wave & 1;       // key-half of tile (keys 32w .. 32w+31)

    const int bid = blockIdx.x;
    const int bh  = bid & 15;
    const int c   = bid >> 4;        // 0..63 chain id
    int nit, qbs[2], t0s[2], t1s[2], mds[2];   // md: 0=direct, 1=A-partial, 2=B-partial
    if (c < 32)      { nit = 1; qbs[0] = 32 + c; t0s[0] = c + 1; t1s[0] = c + 33; mds[0] = 2; }
    else if (c < 48) { int s = c - 32; nit = 2;
                       qbs[0] = 32 + s;  t0s[0] = 0; t1s[0] = s + 1;  mds[0] = 1;
                       qbs[1] = 63 - s;  t0s[1] = 0; t1s[1] = 32 - s; mds[1] = 1; }
    else             { int u = c - 48; nit = 2;
                       qbs[0] = u;       t0s[0] = 0; t1s[0] = u + 1;  mds[0] = 0;
                       qbs[1] = 31 - u;  t0s[1] = 0; t1s[1] = 32 - u; mds[1] = 0; }

    const unsigned short* Qp = Q  + (size_t)bh * (4096 * 64);
    const unsigned short* Kp = K  + (size_t)bh * (4096 * 64);
    const unsigned short* Vp = Vt + (size_t)bh * (64 * 4096);
    const int b = bh >> 3, h = bh & 7;

    short8 ones;
    #pragma unroll
    for (int i = 0; i < 8; ++i) ones[i] = (short)0x3F80;

    // staging geometry: thread covers rows rr, rr+32 at 16B chunk cc; XOR-swizzled
    const int rr  = tid >> 3;
    const int cc  = tid & 7;
    const int c0  = cc * 8;
    const int scs = ((cc ^ (rr & 7)) << 3);

    for (int it = 0; it < nit; ++it) {
        const int qb = qbs[it], t0 = t0s[it], t1 = t1s[it], md = mds[it];
        const int m0 = qb * 64;

        // Q B-frags: col q = m0+32p+l32, k(d) = k16*16 + hh*8 + j
        short8 qf[4];
        #pragma unroll
        for (int k16 = 0; k16 < 4; ++k16)
            qf[k16] = *reinterpret_cast<const short8*>(
                &Qp[(size_t)(m0 + 32 * p + l32) * 64 + k16 * 16 + hh * 8]);

        floatx16 o0 = {0,0,0,0,0,0,0,0,0,0,0,0,0,0,0,0};   // O[q][d=l32]
        floatx16 o1 = {0,0,0,0,0,0,0,0,0,0,0,0,0,0,0,0};   // O[q][d=32+l32]
        floatx16 o4 = {0,0,0,0,0,0,0,0,0,0,0,0,0,0,0,0};   // rowsum (ones-MFMA)

        __syncthreads();   // previous item's epilogue LDS reads done before restage
        const int kb0 = t0 * 64;
        uint4 rk0 = *reinterpret_cast<const uint4*>(&Kp[(size_t)(kb0 + rr) * 64 + c0]);
        uint4 rk1 = *reinterpret_cast<const uint4*>(&Kp[(size_t)(kb0 + rr + 32) * 64 + c0]);
        uint4 rv0 = *reinterpret_cast<const uint4*>(&Vp[(size_t)rr * 4096 + kb0 + c0]);
        uint4 rv1 = *reinterpret_cast<const uint4*>(&Vp[(size_t)(rr + 32) * 4096 + kb0 + c0]);
        *reinterpret_cast<uint4*>(&Kc[0][rr][scs])      = rk0;
        *reinterpret_cast<uint4*>(&Kc[0][rr + 32][scs]) = rk1;
        *reinterpret_cast<uint4*>(&Vc[0][rr][scs])      = rv0;
        *reinterpret_cast<uint4*>(&Vc[0][rr + 32][scs]) = rv1;

        for (int kt = t0; kt < t1; ++kt) {
            __syncthreads();
            const int lt  = kt - t0;
            const int cur = lt & 1;
            const int nxt = cur ^ 1;

            if (kt + 1 < t1) {   // prefetch next tile into registers
                const int jn = (kt + 1) * 64;
                rk0 = *reinterpret_cast<const uint4*>(&Kp[(size_t)(jn + rr) * 64 + c0]);
                rk1 = *reinterpret_cast<const uint4*>(&Kp[(size_t)(jn + rr + 32) * 64 + c0]);
                rv0 = *reinterpret_cast<const uint4*>(&Vp[(size_t)rr * 4096 + jn + c0]);
                rv1 = *reinterpret_cast<const uint4*>(&Vp[(size_t)(rr + 32) * 4096 + jn + c0]);
            }

            // only fully-masked case: q-half 0's key-half 1 on the diagonal tile
            const bool active = (kt < qb) || (w == 0) || (p == 1);
            if (active) {
                // ---- QK^T: S[key][q], A = K rows 32w+l32, B = Q ----
                floatx16 s = {0,0,0,0,0,0,0,0,0,0,0,0,0,0,0,0};
                #pragma unroll
                for (int k16 = 0; k16 < 4; ++k16) {
                    const int chs = ((2 * k16 + hh) ^ swz) << 3;
                    short8 a = *reinterpret_cast<const short8*>(&Kc[cur][32 * w + l32][chs]);
                    s = __builtin_amdgcn_mfma_f32_32x32x16_bf16(a, qf[k16], s, 0, 0, 0);
                }
                if (kt == qb) {   // diagonal: key_local = 32w + (r&3)+8*(r>>2)+4*hh
                    const int ql = 32 * p + l32;
                    #pragma unroll
                    for (int r = 0; r < 16; ++r) {
                        const int kl = 32 * w + (r & 3) + 8 * (r >> 2) + 4 * hh;
                        s[r] = (kl <= ql) ? s[r] : -1e30f;
                    }
                }
                #pragma unroll
                for (int r = 0; r < 16; ++r) s[r] = __builtin_amdgcn_exp2f(s[r]);

                // ---- P -> PV A-frags in registers (r4/r5-verified construction) ----
                unsigned int A0 = pk_bf16(s[0],  s[1]),  B0 = pk_bf16(s[2],  s[3]);
                unsigned int A1 = pk_bf16(s[4],  s[5]),  B1 = pk_bf16(s[6],  s[7]);
                unsigned int A2 = pk_bf16(s[8],  s[9]),  B2 = pk_bf16(s[10], s[11]);
                unsigned int A3 = pk_bf16(s[12], s[13]), B3 = pk_bf16(s[14], s[15]);
                short8 pa[2];
#if HAVE_PLSWAP
                {
                    uint2v rA = __builtin_amdgcn_permlane32_swap(A0, A1, false, false);
                    uint2v rB = __builtin_amdgcn_permlane32_swap(B0, B1, false, false);
                    uint4 u0 = make_uint4(rA[0], rB[0], rA[1], rB[1]);
                    pa[0] = *reinterpret_cast<short8*>(&u0);
                    rA = __builtin_amdgcn_permlane32_swap(A2, A3, false, false);
                    rB = __builtin_amdgcn_permlane32_swap(B2, B3, false, false);
                    uint4 u1 = make_uint4(rA[0], rB[0], rA[1], rB[1]);
                    pa[1] = *reinterpret_cast<short8*>(&u1);
                }
#else
                {
                    unsigned int pA0 = __shfl_xor((int)A0, 32), pA1 = __shfl_xor((int)A1, 32);
                    unsigned int pB0 = __shfl_xor((int)B0, 32), pB1 = __shfl_xor((int)B1, 32);
                    unsigned int pA2 = __shfl_xor((int)A2, 32), pA3 = __shfl_xor((int)A3, 32);
                    unsigned int pB2 = __shfl_xor((int)B2, 32), pB3 = __shfl_xor((int)B3, 32);
                    uint4 u0 = make_uint4(hh ? pA1 : A0, hh ? pB1 : B0,
                                          hh ? A1 : pA0, hh ? B1 : pB0);
                    pa[0] = *reinterpret_cast<short8*>(&u0);
                    uint4 u1 = make_uint4(hh ? pA3 : A2, hh ? pB3 : B2,
                                          hh ? A3 : pA2, hh ? B3 : pB2);
                    pa[1] = *reinterpret_cast<short8*>(&u1);
                }
#endif
                // rowsum on the MFMA pipe (same bf16 P values PV consumes; r6-verified)
                o4 = __builtin_amdgcn_mfma_f32_32x32x16_bf16(pa[0], ones, o4, 0, 0, 0);
                o4 = __builtin_amdgcn_mfma_f32_32x32x16_bf16(pa[1], ones, o4, 0, 0, 0);

                // ---- PV: O[q][d] over key window 32w..32w+31; B = V[key][d] ----
                #pragma unroll
                for (int f = 0; f < 2; ++f) {
                    const int chs = ((4 * w + 2 * f + hh) ^ swz) << 3;
                    short8 b0 = *reinterpret_cast<const short8*>(&Vc[cur][l32][chs]);
                    short8 b1 = *reinterpret_cast<const short8*>(&Vc[cur][32 + l32][chs]);
                    o0 = __builtin_amdgcn_mfma_f32_32x32x16_bf16(pa[f], b0, o0, 0, 0, 0);
                    o1 = __builtin_amdgcn_mfma_f32_32x32x16_bf16(pa[f], b1, o1, 0, 0, 0);
                }
            }

            if (kt + 1 < t1) {   // stage prefetched tile into the idle buffer
                *reinterpret_cast<uint4*>(&Kc[nxt][rr][scs])      = rk0;
                *reinterpret_cast<uint4*>(&Kc[nxt][rr + 32][scs]) = rk1;
                *reinterpret_cast<uint4*>(&Vc[nxt][rr][scs])      = rv0;
                *reinterpret_cast<uint4*>(&Vc[nxt][rr + 32][scs]) = rv1;
            }
        }

        // ---- epilogue: combine partial O + rowsum across the wave pair via LDS ----
        __syncthreads();                                       // all tile reads done
        float* Ob  = reinterpret_cast<float*>(&Kc[0][0][0]);   // [4][32][32] f32 = 16 KB
        float* Wsf = reinterpret_cast<float*>(&Vc[0][0][0]);   // [4][32] rowsums by q
        if (l32 == 0) {
            #pragma unroll
            for (int r = 0; r < 16; ++r) {
                const int qloc = (r & 3) + 8 * (r >> 2) + 4 * hh;
                Wsf[(p * 2 + w) * 32 + qloc] = o4[r];          // o4 duplicated over cols
            }
        }
        #pragma unroll
        for (int r = 0; r < 16; ++r) {                         // give away partner half
            const int qloc = (r & 3) + 8 * (r >> 2) + 4 * hh;
            Ob[((p * 2 + w) * 32 + qloc) * 32 + l32] = w ? o0[r] : o1[r];
        }
        __syncthreads();

        float cmb[16], rt[16];
        #pragma unroll
        for (int gg = 0; gg < 4; ++gg) {
            float4 a4 = *reinterpret_cast<const float4*>(&Wsf[(p * 2 + 0) * 32 + 8 * gg + 4 * hh]);
            float4 b4 = *reinterpret_cast<const float4*>(&Wsf[(p * 2 + 1) * 32 + 8 * gg + 4 * hh]);
            const float ra[4] = {a4.x + b4.x, a4.y + b4.y, a4.z + b4.z, a4.w + b4.w};
            #pragma unroll
            for (int rsub = 0; rsub < 4; ++rsub) {
                const int r = gg * 4 + rsub;
                const int qloc = 8 * gg + 4 * hh + rsub;
                cmb[r] = (w ? o1[r] : o0[r]) + Ob[((p * 2 + (1 - w)) * 32 + qloc) * 32 + l32];
                rt[r]  = ra[rsub];
            }
        }

        if (md == 0) {
            #pragma unroll
            for (int r = 0; r < 16; ++r) {
                const int qloc = (r & 3) + 8 * (r >> 2) + 4 * hh;
                const int t = m0 + 32 * p + qloc;
                Y[((size_t)(b * 4096 + t)) * 512 + h * 64 + 32 * w + l32]
                    = f2bf(cmb[r] / rt[r]);
            }
        } else {
            // partial: O -> slot (A or B half of d_out), rowsum -> f32 stash inside
            // the Y rows attn_fin will read-then-overwrite (rows qb*64 + half*2 +0/1)
            const int half = md - 1;                           // 0 = A, 1 = B
            float* slot = scratch + ((size_t)(half * 512 + (qb - 32) * 16 + bh)) * 4096;
            #pragma unroll
            for (int r = 0; r < 16; ++r) {
                const int qloc = (r & 3) + 8 * (r >> 2) + 4 * hh;
                slot[(32 * p + qloc) * 64 + 32 * w + l32] = cmb[r];
            }
            if (w == 0 && l32 == 0) {
                float* rsp = reinterpret_cast<float*>(
                    &Y[((size_t)(b * 4096 + qb * 64 + half * 2)) * 512 + h * 64]);
                #pragma unroll
                for (int r = 0; r < 16; ++r) {
                    const int qloc = (r & 3) + 8 * (r >> 2) + 4 * hh;
                    const int q64 = 32 * p + qloc;
                    rsp[(q64 >> 5) * 256 + (q64 & 31)] = rt[r];
                }
            }
        }
    }
}

// ---------------- attn_fin: combine A+B partials for split rows, write Y bf16 --------
__global__ __launch_bounds__(256) void attn_fin(
    const float* __restrict__ scratch, unsigned short* __restrict__ Y)
{
    const int bid = blockIdx.x;          // 512 = 32 split qb x 16 bh
    const int bh  = bid & 15;
    const int q32 = bid >> 4;
    const int qb  = 32 + q32;
    const int b = bh >> 3, h = bh & 7;

    const float* sA = scratch + ((size_t)(q32 * 16 + bh)) * 4096;
    const float* sB = sA + (size_t)512 * 4096;

    const int q64 = threadIdx.x >> 2;
    const int d0  = (threadIdx.x & 3) * 16;

    const float* rsA = reinterpret_cast<const float*>(
        &Y[((size_t)(b * 4096 + qb * 64 + 0)) * 512 + h * 64]);
    const float* rsB = reinterpret_cast<const float*>(
        &Y[((size_t)(b * 4096 + qb * 64 + 2)) * 512 + h * 64]);
    const float ra = rsA[(q64 >> 5) * 256 + (q64 & 31)]
                   + rsB[(q64 >> 5) * 256 + (q64 & 31)];
    __syncthreads();                      // all rs reads done before Y rows overwritten
    const float inv = 1.0f / ra;

    unsigned short* yr = &Y[((size_t)(b * 4096 + qb * 64 + q64)) * 512 + h * 64 + d0];
    unsigned short obuf[16];
    #pragma unroll
    for (int i = 0; i < 16; i += 4) {
        float4 a = *reinterpret_cast<const float4*>(&sA[(size_t)q64 * 64 + d0 + i]);
        float4 bb = *reinterpret_cast<const float4*>(&sB[(size_t)q64 * 64 + d0 + i]);
        obuf[i]     = f2bf((a.x + bb.x) * inv);
        obuf[i + 1] = f2bf((a.y + bb.y) * inv);
        obuf[i + 2] = f2bf((a.z + bb.z) * inv);
        obuf[i + 3] = f2bf((a.w + bb.w) * inv);
    }
    *reinterpret_cast<uint4*>(yr)     = *reinterpret_cast<uint4*>(&obuf[0]);
    *reinterpret_cast<uint4*>(yr + 8) = *reinterpret_cast<uint4*>(&obuf[8]);
}

extern "C" void kernel_launch(void* const* d_in, const int* in_sizes, int n_in,
                              void* d_out, int out_size, void* d_ws, size_t ws_size,
                              hipStream_t stream) {
    const float* x  = (const float*)d_in[0];
    const float* Wa = (const float*)d_in[1];
    const float* Wp = (const float*)d_in[2];
    float* out = (float*)d_out;
    unsigned short* ws = (unsigned short*)d_ws;

    unsigned short* Qb  = ws;
    unsigned short* Kb  = ws + 4194304;
    unsigned short* Vtb = ws + 8388608;
    unsigned short* Yb  = ws + 12582912;
    unsigned short* WaT = Yb;                      // W_attn^T during QKV only
    unsigned short* WpT = Qb;                      // W_proj^T after attn (Q dead)
    unsigned short* xb  = (unsigned short*)d_out;  // x bf16; dead after mm_bt<0>
    float* scratch = (float*)d_out;                // A/B partial O slots during attn

    prep_a<<<dim3(2816), dim3(256), 0, stream>>>(x, xb, Wa, WaT);
    mm_bt<0><<<dim3(64, 12), dim3(256), 0, stream>>>(xb, WaT, (void*)ws);
    attn_mfma<<<dim3(1024), dim3(256), 0, stream>>>(Qb, Kb, Vtb, Yb, scratch);
    attn_fin<<<dim3(512), dim3(256), 0, stream>>>(scratch, Yb);
    transpose_wp<<<dim3(16, 16), dim3(256), 0, stream>>>(Wp, WpT);
    mm_bt<1><<<dim3(64, 4), dim3(256), 0, stream>>>(Yb, WpT, (void*)out);
}

// Round 8
// 162.761 us; speedup vs baseline: 1.8075x; 1.2269x over previous
//
#include <hip/hip_runtime.h>
#include <hip/hip_bf16.h>
#include <stdint.h>

// B=2, T=4096, C=512, H=8, D=64. Inputs fp32, output fp32, internals bf16.
// ws (bf16 elems), 32 MiB:
//   Q  [0        .. 4194304)   [B,H,T,D]  (pre-scaled by 0.125*log2e)
//   K  [4194304  .. 8388608)   [B,H,T,D]
//   Vt [8388608  .. 12582912)  [B,H,D,T]
//   Y  [12582912 .. 16777216)  [B,T,C]    (WaT here during QKV; clobbered by attn)
// WpT -> Q region after attn (Q dead). xb (x bf16) in d_out until proj overwrites.

typedef __attribute__((ext_vector_type(8))) short short8;
typedef __attribute__((ext_vector_type(4))) float floatx4;
typedef __attribute__((ext_vector_type(16))) float floatx16;
#if __has_builtin(__builtin_amdgcn_permlane32_swap)
typedef __attribute__((ext_vector_type(2))) unsigned int uint2v;
#define HAVE_PLSWAP 1
#else
#define HAVE_PLSWAP 0
#endif

__device__ __forceinline__ unsigned short f2bf(float f) {
    unsigned int x = __float_as_uint(f);
    unsigned int r = x + 0x7fffu + ((x >> 16) & 1u);
    return (unsigned short)(r >> 16);
}

__device__ __forceinline__ unsigned int pk_bf16(float a, float b) {
    __hip_bfloat162 p = __float22bfloat162_rn(make_float2(a, b));  // v_cvt_pk_bf16_f32
    return *reinterpret_cast<unsigned int*>(&p);
}

// ---------------- P0: fused prep: convert x (blocks 0..2047) + W_attn^T (2048..2815) --
__global__ __launch_bounds__(256) void prep_a(
    const float* __restrict__ x, unsigned short* __restrict__ xb,
    const float* __restrict__ Wa, unsigned short* __restrict__ WaT)
{
    const int bid = blockIdx.x;
    const int tid = threadIdx.x;
    if (bid < 2048) {
        size_t i = ((size_t)bid * 256 + tid) * 8;
        float4 a = *reinterpret_cast<const float4*>(x + i);
        float4 b = *reinterpret_cast<const float4*>(x + i + 4);
        unsigned short o[8] = {f2bf(a.x), f2bf(a.y), f2bf(a.z), f2bf(a.w),
                               f2bf(b.x), f2bf(b.y), f2bf(b.z), f2bf(b.w)};
        *reinterpret_cast<uint4*>(xb + i) = *reinterpret_cast<uint4*>(o);
    } else {
        __shared__ unsigned short tile[32][34];
        const int t2 = bid - 2048;           // 48 n-tiles x 16 k-tiles
        const int n0 = (t2 % 48) * 32, k0 = (t2 / 48) * 32;
        const int tx = tid & 31, ty = tid >> 5;
        #pragma unroll
        for (int p = 0; p < 4; ++p)
            tile[tx][ty + p * 8] = f2bf(Wa[(size_t)(k0 + ty + p * 8) * 1536 + n0 + tx]);
        __syncthreads();
        #pragma unroll
        for (int p = 0; p < 4; ++p)
            WaT[(size_t)(n0 + ty + p * 8) * 512 + k0 + tx] = tile[ty + p * 8][tx];
    }
}

// ---------------- P1: W_proj [512][512] fp32 -> WpT [512][512] bf16 -------------------
__global__ __launch_bounds__(256) void transpose_wp(
    const float* __restrict__ W, unsigned short* __restrict__ Wt)
{
    __shared__ unsigned short tile[32][34];
    const int tid = threadIdx.x;
    const int tx = tid & 31, ty = tid >> 5;
    const int n0 = blockIdx.x * 32, k0 = blockIdx.y * 32;
    #pragma unroll
    for (int p = 0; p < 4; ++p)
        tile[tx][ty + p * 8] = f2bf(W[(size_t)(k0 + ty + p * 8) * 512 + n0 + tx]);
    __syncthreads();
    #pragma unroll
    for (int p = 0; p < 4; ++p)
        Wt[(size_t)(n0 + ty + p * 8) * 512 + k0 + tx] = tile[ty + p * 8][tx];
}

// ---------------- MFMA GEMM (r16-proven): 128x128, BK=32, LDS dbuf, 1 barrier/iter ----
template<int EPI>
__global__ __launch_bounds__(256) void mm_bt(
    const unsigned short* __restrict__ A,
    const unsigned short* __restrict__ Bt,
    void* __restrict__ outp)
{
    __shared__ __align__(16) unsigned char smem[40960];

    const int tid  = threadIdx.x;
    const int wave = tid >> 6;
    const int lane = tid & 63;
    const int quad = lane >> 4;
    const int l16  = lane & 15;
    const int wr   = wave >> 1;
    const int wc   = wave & 1;
    const int m0 = blockIdx.x * 128;
    const int n0 = blockIdx.y * 128;

    floatx4 acc[4][4];
    #pragma unroll
    for (int i = 0; i < 4; ++i)
        #pragma unroll
        for (int j = 0; j < 4; ++j) acc[i][j] = (floatx4){0.f, 0.f, 0.f, 0.f};

    const int row = tid >> 1;
    const int cb  = (tid & 1) * 16;

    const unsigned short* ap = &A[(size_t)(m0 + row) * 512 + cb];
    const unsigned short* bp = &Bt[(size_t)(n0 + row) * 512 + cb];

    uint4 ra0 = *reinterpret_cast<const uint4*>(ap);
    uint4 ra1 = *reinterpret_cast<const uint4*>(ap + 8);
    uint4 rb0 = *reinterpret_cast<const uint4*>(bp);
    uint4 rb1 = *reinterpret_cast<const uint4*>(bp + 8);
    {
        auto Al = reinterpret_cast<unsigned short(*)[40]>(smem);
        auto Bl = reinterpret_cast<unsigned short(*)[40]>(smem + 10240);
        *reinterpret_cast<uint4*>(&Al[row][cb])     = ra0;
        *reinterpret_cast<uint4*>(&Al[row][cb + 8]) = ra1;
        *reinterpret_cast<uint4*>(&Bl[row][cb])     = rb0;
        *reinterpret_cast<uint4*>(&Bl[row][cb + 8]) = rb1;
    }

    for (int it = 0; it < 16; ++it) {
        __syncthreads();
        const int k0 = it * 32;
        if (it < 15) {
            ra0 = *reinterpret_cast<const uint4*>(ap + k0 + 32);
            ra1 = *reinterpret_cast<const uint4*>(ap + k0 + 40);
            rb0 = *reinterpret_cast<const uint4*>(bp + k0 + 32);
            rb1 = *reinterpret_cast<const uint4*>(bp + k0 + 40);
        }

        auto Al = reinterpret_cast<unsigned short(*)[40]>(smem + (it & 1) * 20480);
        auto Bl = reinterpret_cast<unsigned short(*)[40]>(smem + (it & 1) * 20480 + 10240);

        short8 af[4], bf[4];
        #pragma unroll
        for (int ti = 0; ti < 4; ++ti)
            af[ti] = *reinterpret_cast<const short8*>(&Al[wr * 64 + ti * 16 + l16][quad * 8]);
        #pragma unroll
        for (int tj = 0; tj < 4; ++tj)
            bf[tj] = *reinterpret_cast<const short8*>(&Bl[wc * 64 + tj * 16 + l16][quad * 8]);
        #pragma unroll
        for (int ti = 0; ti < 4; ++ti)
            #pragma unroll
            for (int tj = 0; tj < 4; ++tj)
                acc[ti][tj] = __builtin_amdgcn_mfma_f32_16x16x32_bf16(af[ti], bf[tj], acc[ti][tj], 0, 0, 0);

        if (it < 15) {
            auto An = reinterpret_cast<unsigned short(*)[40]>(smem + ((it + 1) & 1) * 20480);
            auto Bn = reinterpret_cast<unsigned short(*)[40]>(smem + ((it + 1) & 1) * 20480 + 10240);
            *reinterpret_cast<uint4*>(&An[row][cb])     = ra0;
            *reinterpret_cast<uint4*>(&An[row][cb + 8]) = ra1;
            *reinterpret_cast<uint4*>(&Bn[row][cb])     = rb0;
            *reinterpret_cast<uint4*>(&Bn[row][cb + 8]) = rb1;
        }
    }

    if (EPI == 0) {
        unsigned short* WS = (unsigned short*)outp;
        unsigned short* Qb  = WS;
        unsigned short* Kb  = WS + 4194304;
        unsigned short* Vtb = WS + 8388608;
        const int which = n0 >> 9;
        const int h = ((n0 + wc * 64) >> 6) & 7;

        if (which == 2) {
            auto Tr = reinterpret_cast<unsigned short(*)[80]>(smem);   // [256][80]
            __syncthreads();
            #pragma unroll
            for (int ti = 0; ti < 4; ++ti)
                #pragma unroll
                for (int tj = 0; tj < 4; ++tj) {
                    unsigned int lo = pk_bf16(acc[ti][tj][0], acc[ti][tj][1]);
                    unsigned int hi = pk_bf16(acc[ti][tj][2], acc[ti][tj][3]);
                    *reinterpret_cast<uint2*>(&Tr[(wave << 6) + tj * 16 + l16][ti * 16 + quad * 4])
                        = make_uint2(lo, hi);
                }
            const int b = m0 >> 12;
            const int bh = b * 8 + h;
            const int t0g = (m0 & 4095) + wr * 64;
            const int tseg = (lane & 7) * 8;
            #pragma unroll
            for (int p = 0; p < 8; ++p) {
                int dl = p * 8 + (lane >> 3);
                uint4 v = *reinterpret_cast<const uint4*>(&Tr[(wave << 6) + dl][tseg]);
                *reinterpret_cast<uint4*>(&Vtb[((size_t)(bh * 64 + dl)) * 4096 + t0g + tseg]) = v;
            }
        } else {
            const float sc = (which == 0) ? 0.18033688f : 1.0f;  // 0.125*log2(e)
            #pragma unroll
            for (int ti = 0; ti < 4; ++ti) {
                #pragma unroll
                for (int r = 0; r < 4; ++r) {
                    int m = m0 + wr * 64 + ti * 16 + quad * 4 + r;
                    int b = m >> 12, t = m & 4095;
                    int bh = b * 8 + h;
                    #pragma unroll
                    for (int tj = 0; tj < 4; ++tj) {
                        int d = tj * 16 + l16;
                        unsigned short val = f2bf(acc[ti][tj][r] * sc);
                        if (which == 0) Qb[((size_t)bh * 4096 + t) * 64 + d] = val;
                        else            Kb[((size_t)bh * 4096 + t) * 64 + d] = val;
                    }
                }
            }
        }
    } else {
        float* Out = (float*)outp;
        #pragma unroll
        for (int ti = 0; ti < 4; ++ti) {
            #pragma unroll
            for (int r = 0; r < 4; ++r) {
                int m = m0 + wr * 64 + ti * 16 + quad * 4 + r;
                #pragma unroll
                for (int tj = 0; tj < 4; ++tj) {
                    int n = n0 + wc * 64 + tj * 16 + l16;
                    Out[(size_t)m * 512 + n] = acc[ti][tj][r];
                }
            }
        }
    }
}

// ---------------- MFMA flash attention: r5 geometry + VALU diet -----------------------
// Block = 64 q-rows, 256 threads, 1024 blocks (64 qb x 16 bh), balanced permutation,
// 4 blocks/CU resident (LDS 32 KB) -- r5's proven geometry (67.5 us, VALUBusy 57.7%).
// Wave (p = wave>>1, w = wave&1): q-rows m0+32p..+31 vs key half 32w..32w+31.
// ONLY changes vs r5 (both r7-verified numerically, zero schedule risk):
//  1. rowsum via ones-MFMA into o4 (removes 8x bfsum2 unpack+add chains ~64 VALU
//     issue-cyc/wave-tile from the binding VALU pipe; epilogue = r7 md==0 path).
//  2. incremental prefetch pointers (kq += 4096, vq += 64) instead of per-tile
//     64-bit address recompute.
__global__ __launch_bounds__(256) void attn_mfma(
    const unsigned short* __restrict__ Q,
    const unsigned short* __restrict__ K,
    const unsigned short* __restrict__ Vt,
    unsigned short* __restrict__ Y)
{
    __shared__ __align__(16) unsigned short Kc[2][64][64];
    __shared__ __align__(16) unsigned short Vc[2][64][64];

    const int tid  = threadIdx.x;
    const int wave = tid >> 6;
    const int lane = tid & 63;
    const int l32  = lane & 31;
    const int hh   = lane >> 5;
    const int swz  = l32 & 7;
    const int p    = wave >> 1;      // q-half of block (rows m0+32p .. +31)
    const int w    = wave & 1;       // key-half of tile (keys 32w .. 32w+31)

    // balanced qb permutation (r3/r5-proven): per-CU tile count = const 130
    const int bid = blockIdx.x;
    const int bh  = bid & 15;
    const int j   = (bid >> 4) & 15;
    const int g   = bid >> 8;
    const int qb  = (g == 0) ? j : (g == 1) ? (63 - j) : (g == 2) ? (16 + j) : (47 - j);
    const int m0  = qb * 64;

    const unsigned short* Qp = Q  + (size_t)bh * (4096 * 64);
    const unsigned short* Kp = K  + (size_t)bh * (4096 * 64);
    const unsigned short* Vp = Vt + (size_t)bh * (64 * 4096);

    // Q B-frags (pre-scaled upstream): col q = m0+32p+l32, k(d) = k16*16 + hh*8 + jj
    short8 qf[4];
    #pragma unroll
    for (int k16 = 0; k16 < 4; ++k16)
        qf[k16] = *reinterpret_cast<const short8*>(
            &Qp[(size_t)(m0 + 32 * p + l32) * 64 + k16 * 16 + hh * 8]);

    short8 ones;
    #pragma unroll
    for (int i = 0; i < 8; ++i) ones[i] = (short)0x3F80;

    floatx16 o0 = {0,0,0,0,0,0,0,0,0,0,0,0,0,0,0,0};   // O[q][d=l32]
    floatx16 o1 = {0,0,0,0,0,0,0,0,0,0,0,0,0,0,0,0};   // O[q][d=32+l32]
    floatx16 o4 = {0,0,0,0,0,0,0,0,0,0,0,0,0,0,0,0};   // rowsum (ones-MFMA)

    // staging: thread covers rows rr, rr+32 at 16B chunk cc; XOR-swizzled (r1-proven)
    const int rr  = tid >> 3;
    const int cc  = tid & 7;
    const int c0  = cc * 8;
    const int scs = ((cc ^ (rr & 7)) << 3);

    uint4 rk0 = *reinterpret_cast<const uint4*>(&Kp[(size_t)rr * 64 + c0]);
    uint4 rk1 = *reinterpret_cast<const uint4*>(&Kp[(size_t)(rr + 32) * 64 + c0]);
    uint4 rv0 = *reinterpret_cast<const uint4*>(&Vp[(size_t)rr * 4096 + c0]);
    uint4 rv1 = *reinterpret_cast<const uint4*>(&Vp[(size_t)(rr + 32) * 4096 + c0]);
    *reinterpret_cast<uint4*>(&Kc[0][rr][scs])      = rk0;
    *reinterpret_cast<uint4*>(&Kc[0][rr + 32][scs]) = rk1;
    *reinterpret_cast<uint4*>(&Vc[0][rr][scs])      = rv0;
    *reinterpret_cast<uint4*>(&Vc[0][rr + 32][scs]) = rv1;

    // incremental prefetch pointers (tile 1 positions)
    const unsigned short* kq0 = Kp + (size_t)(64 + rr) * 64 + c0;
    const unsigned short* kq1 = Kp + (size_t)(64 + rr + 32) * 64 + c0;
    const unsigned short* vq0 = Vp + (size_t)rr * 4096 + 64 + c0;
    const unsigned short* vq1 = Vp + (size_t)(rr + 32) * 4096 + 64 + c0;

    const int NT = qb + 1;
    for (int kt = 0; kt < NT; ++kt) {
        __syncthreads();
        const int cur = kt & 1;
        const int nxt = cur ^ 1;

        if (kt + 1 < NT) {   // prefetch next tile into registers
            rk0 = *reinterpret_cast<const uint4*>(kq0);
            rk1 = *reinterpret_cast<const uint4*>(kq1);
            rv0 = *reinterpret_cast<const uint4*>(vq0);
            rv1 = *reinterpret_cast<const uint4*>(vq1);
            kq0 += 4096; kq1 += 4096; vq0 += 64; vq1 += 64;
        }

        // only fully-masked case: q-half 0's key-half 1 on the diagonal tile
        const bool active = (kt < qb) || (w == 0) || (p == 1);
        if (active) {
            // ---- QK^T: S[key][q], A = K rows 32w+l32, B = Q ----
            floatx16 s = {0,0,0,0,0,0,0,0,0,0,0,0,0,0,0,0};
            #pragma unroll
            for (int k16 = 0; k16 < 4; ++k16) {
                const int chs = ((2 * k16 + hh) ^ swz) << 3;
                short8 a = *reinterpret_cast<const short8*>(&Kc[cur][32 * w + l32][chs]);
                s = __builtin_amdgcn_mfma_f32_32x32x16_bf16(a, qf[k16], s, 0, 0, 0);
            }
            if (kt == qb) {   // diagonal: key_local = 32w + (r&3)+8*(r>>2)+4*hh
                const int ql = 32 * p + l32;
                #pragma unroll
                for (int r = 0; r < 16; ++r) {
                    const int kl = 32 * w + (r & 3) + 8 * (r >> 2) + 4 * hh;
                    s[r] = (kl <= ql) ? s[r] : -1e30f;
                }
            }
            #pragma unroll
            for (int r = 0; r < 16; ++r) s[r] = __builtin_amdgcn_exp2f(s[r]);

            // ---- P -> PV A-frags in registers (r4/r5-verified construction) ----
            unsigned int A0 = pk_bf16(s[0],  s[1]),  B0 = pk_bf16(s[2],  s[3]);
            unsigned int A1 = pk_bf16(s[4],  s[5]),  B1 = pk_bf16(s[6],  s[7]);
            unsigned int A2 = pk_bf16(s[8],  s[9]),  B2 = pk_bf16(s[10], s[11]);
            unsigned int A3 = pk_bf16(s[12], s[13]), B3 = pk_bf16(s[14], s[15]);
            short8 pa[2];
#if HAVE_PLSWAP
            {
                uint2v rA = __builtin_amdgcn_permlane32_swap(A0, A1, false, false);
                uint2v rB = __builtin_amdgcn_permlane32_swap(B0, B1, false, false);
                uint4 u0 = make_uint4(rA[0], rB[0], rA[1], rB[1]);
                pa[0] = *reinterpret_cast<short8*>(&u0);
                rA = __builtin_amdgcn_permlane32_swap(A2, A3, false, false);
                rB = __builtin_amdgcn_permlane32_swap(B2, B3, false, false);
                uint4 u1 = make_uint4(rA[0], rB[0], rA[1], rB[1]);
                pa[1] = *reinterpret_cast<short8*>(&u1);
            }
#else
            {
                unsigned int pA0 = __shfl_xor((int)A0, 32), pA1 = __shfl_xor((int)A1, 32);
                unsigned int pB0 = __shfl_xor((int)B0, 32), pB1 = __shfl_xor((int)B1, 32);
                unsigned int pA2 = __shfl_xor((int)A2, 32), pA3 = __shfl_xor((int)A3, 32);
                unsigned int pB2 = __shfl_xor((int)B2, 32), pB3 = __shfl_xor((int)B3, 32);
                uint4 u0 = make_uint4(hh ? pA1 : A0, hh ? pB1 : B0,
                                      hh ? A1 : pA0, hh ? B1 : pB0);
                pa[0] = *reinterpret_cast<short8*>(&u0);
                uint4 u1 = make_uint4(hh ? pA3 : A2, hh ? pB3 : B2,
                                      hh ? A3 : pA2, hh ? B3 : pB2);
                pa[1] = *reinterpret_cast<short8*>(&u1);
            }
#endif
            // rowsum on the MFMA pipe (same bf16 P values PV consumes; r7-verified)
            o4 = __builtin_amdgcn_mfma_f32_32x32x16_bf16(pa[0], ones, o4, 0, 0, 0);
            o4 = __builtin_amdgcn_mfma_f32_32x32x16_bf16(pa[1], ones, o4, 0, 0, 0);

            // ---- PV: O[q][d] over key window 32w..32w+31; B = V[key][d] ----
            #pragma unroll
            for (int f = 0; f < 2; ++f) {
                const int chs = ((4 * w + 2 * f + hh) ^ swz) << 3;
                short8 b0 = *reinterpret_cast<const short8*>(&Vc[cur][l32][chs]);
                short8 b1 = *reinterpret_cast<const short8*>(&Vc[cur][32 + l32][chs]);
                o0 = __builtin_amdgcn_mfma_f32_32x32x16_bf16(pa[f], b0, o0, 0, 0, 0);
                o1 = __builtin_amdgcn_mfma_f32_32x32x16_bf16(pa[f], b1, o1, 0, 0, 0);
            }
        }

        if (kt + 1 < NT) {   // stage prefetched tile into the idle buffer
            *reinterpret_cast<uint4*>(&Kc[nxt][rr][scs])      = rk0;
            *reinterpret_cast<uint4*>(&Kc[nxt][rr + 32][scs]) = rk1;
            *reinterpret_cast<uint4*>(&Vc[nxt][rr][scs])      = rv0;
            *reinterpret_cast<uint4*>(&Vc[nxt][rr + 32][scs]) = rv1;
        }
    }

    // ---- epilogue (r7-verified md==0 path): combine across wave pair via LDS ----
    __syncthreads();                                       // all tile reads done
    float* Ob  = reinterpret_cast<float*>(&Kc[0][0][0]);   // [4][32][32] f32 = 16 KB
    float* Wsf = reinterpret_cast<float*>(&Vc[0][0][0]);   // [4][32] rowsums by q
    if (l32 == 0) {
        #pragma unroll
        for (int r = 0; r < 16; ++r) {
            const int qloc = (r & 3) + 8 * (r >> 2) + 4 * hh;
            Wsf[(p * 2 + w) * 32 + qloc] = o4[r];          // o4 duplicated over cols
        }
    }
    #pragma unroll
    for (int r = 0; r < 16; ++r) {                         // give away partner half
        const int qloc = (r & 3) + 8 * (r >> 2) + 4 * hh;
        Ob[((p * 2 + w) * 32 + qloc) * 32 + l32] = w ? o0[r] : o1[r];
    }
    __syncthreads();

    const int b = bh >> 3, h = bh & 7;
    #pragma unroll
    for (int gg = 0; gg < 4; ++gg) {
        float4 a4 = *reinterpret_cast<const float4*>(&Wsf[(p * 2 + 0) * 32 + 8 * gg + 4 * hh]);
        float4 b4 = *reinterpret_cast<const float4*>(&Wsf[(p * 2 + 1) * 32 + 8 * gg + 4 * hh]);
        const float ra[4] = {a4.x + b4.x, a4.y + b4.y, a4.z + b4.z, a4.w + b4.w};
        #pragma unroll
        for (int rsub = 0; rsub < 4; ++rsub) {
            const int r = gg * 4 + rsub;
            const int qloc = 8 * gg + 4 * hh + rsub;
            const float cmb = (w ? o1[r] : o0[r])
                            + Ob[((p * 2 + (1 - w)) * 32 + qloc) * 32 + l32];
            const int t = m0 + 32 * p + qloc;
            Y[((size_t)(b * 4096 + t)) * 512 + h * 64 + 32 * w + l32]
                = f2bf(cmb / ra[rsub]);
        }
    }
}

extern "C" void kernel_launch(void* const* d_in, const int* in_sizes, int n_in,
                              void* d_out, int out_size, void* d_ws, size_t ws_size,
                              hipStream_t stream) {
    const float* x  = (const float*)d_in[0];
    const float* Wa = (const float*)d_in[1];
    const float* Wp = (const float*)d_in[2];
    float* out = (float*)d_out;
    unsigned short* ws = (unsigned short*)d_ws;

    unsigned short* Qb  = ws;
    unsigned short* Kb  = ws + 4194304;
    unsigned short* Vtb = ws + 8388608;
    unsigned short* Yb  = ws + 12582912;
    unsigned short* WaT = Yb;                      // W_attn^T during QKV only
    unsigned short* WpT = Qb;                      // W_proj^T after attn (Q dead)
    unsigned short* xb  = (unsigned short*)d_out;  // x bf16; overwritten by proj

    prep_a<<<dim3(2816), dim3(256), 0, stream>>>(x, xb, Wa, WaT);
    mm_bt<0><<<dim3(64, 12), dim3(256), 0, stream>>>(xb, WaT, (void*)ws);
    attn_mfma<<<dim3(1024), dim3(256), 0, stream>>>(Qb, Kb, Vtb, Yb);
    transpose_wp<<<dim3(16, 16), dim3(256), 0, stream>>>(Wp, WpT);
    mm_bt<1><<<dim3(64, 4), dim3(256), 0, stream>>>(Yb, WpT, (void*)out);
}